// Round 1
// baseline (356.034 us; speedup 1.0000x reference)
//
#include <hip/hip_runtime.h>
#include <hip/hip_bf16.h>
#include <stdint.h>

// ---------------------------------------------------------------------------
// PoseFeatureExtractor fused kernel for MI355X (gfx950)
//   prep_kernel : fold BN into W1/b1, bf16-convert + MFMA-B-fragment-pack W1/W2
//   pose_mlp    : feature extraction + 2-layer MLP, fully fused per 64-token tile
// ---------------------------------------------------------------------------

#define S_    2048
#define MT_   64            // tokens per block (2048 % 64 == 0 -> no b straddle)
#define KPAD_ 320           // 300 padded to 10 K-chunks of 32
#define HID_  256
#define OUT_  128

typedef __attribute__((ext_vector_type(8))) short   short8;   // bf16x8 MFMA frag
typedef __attribute__((ext_vector_type(4))) float   floatx4;  // fp32x4 MFMA acc

__constant__ int d_c0[13] = {0,1,1,5,7,6,8,1,1,11,13,12,14};
__constant__ int d_c1[13] = {1,5,6,7,9,8,10,11,12,13,15,14,16};

__device__ __forceinline__ unsigned short bf16_bits(float v) {
    union { float f; unsigned u; } x; x.f = v;
    unsigned r = x.u + 0x7fffu + ((x.u >> 16) & 1u);   // RNE
    return (unsigned short)(r >> 16);
}

__device__ __forceinline__ void async16(void* lds, const void* g) {
    __builtin_amdgcn_global_load_lds(
        (const __attribute__((address_space(1))) unsigned int*)g,
        (__attribute__((address_space(3))) unsigned int*)lds,
        16, 0, 0);
}

// --------------------------- prep kernel -----------------------------------
// B-fragment packing for 16x16x32 bf16 MFMA:
//   lane l holds B[k = (l>>4)*8 + j][n = l&15], j=0..7
//   tile (kc=k>>5, nt=n>>4) is a contiguous 1KB block; within: (kq*16+nr)*8 + j
__global__ void prep_kernel(const float* __restrict__ W1, const float* __restrict__ b1,
                            const float* __restrict__ gamma, const float* __restrict__ beta,
                            const float* __restrict__ rmean, const float* __restrict__ rvar,
                            const float* __restrict__ W2,
                            unsigned short* __restrict__ w1p,
                            unsigned short* __restrict__ w2p,
                            float* __restrict__ b1p) {
    int idx = blockIdx.x * 256 + threadIdx.x;
    if (idx < KPAD_ * HID_) {                       // 81920: W1 folded+packed
        int k = idx >> 8, n = idx & 255;
        float a = gamma[n] * rsqrtf(rvar[n] + 1e-5f);
        float v = (k < 300) ? W1[k * HID_ + n] * a : 0.f;
        int blk = (k >> 5) * 16 + (n >> 4);         // kc-major, 16 nt per kc
        int off = blk * 512 + (((k >> 3) & 3) * 16 + (n & 15)) * 8 + (k & 7);
        w1p[off] = bf16_bits(v);
    } else if (idx < KPAD_ * HID_ + HID_ * OUT_) {  // 32768: W2 packed
        int i2 = idx - KPAD_ * HID_;
        int k = i2 >> 7, n = i2 & 127;
        int blk = (k >> 5) * 8 + (n >> 4);          // kc-major, 8 nt per kc
        int off = blk * 512 + (((k >> 3) & 3) * 16 + (n & 15)) * 8 + (k & 7);
        w2p[off] = bf16_bits(W2[k * OUT_ + n]);
    } else if (idx < KPAD_ * HID_ + HID_ * OUT_ + HID_) {   // 256: folded bias
        int n = idx - (KPAD_ * HID_ + HID_ * OUT_);
        float a = gamma[n] * rsqrtf(rvar[n] + 1e-5f);
        b1p[n] = a * (b1[n] - rmean[n]) + beta[n];
    }
}

// --------------------------- main fused kernel ------------------------------
// LDS layout (bytes):
//   [0, 41984)        feat tile: 64 rows x 328 ushort (656B stride, 16B-mult)
//                     later reused as hidden: 64 rows x 264 ushort (528B stride)
//   [41984, 74752)    W double-buffer 2x16KB; in phase0 reused as:
//                     pose buffer 66x75 fp32 (19800B) + root/scale float4[66]
#define LDS_FEAT  0
#define LDS_WB    41984
#define LDS_RS    (LDS_WB + 19808)
#define LDS_TOTAL (41984 + 32768)

__global__ __launch_bounds__(256, 2) void pose_mlp(
    const float* __restrict__ poses,
    const unsigned short* __restrict__ w1p,
    const unsigned short* __restrict__ w2p,
    const float* __restrict__ b1p,
    const float* __restrict__ b2,
    const float* __restrict__ jw,
    float* __restrict__ out)
{
    __shared__ __align__(16) unsigned char smem[LDS_TOTAL];
    const int tid  = threadIdx.x;
    const int lane = tid & 63;
    const int wv   = tid >> 6;
    const int t0   = blockIdx.x * MT_;
    const int s0   = t0 & (S_ - 1);

    // ---------------- phase 0: features ----------------
    float*  pbuf = (float*)(smem + LDS_WB);
    float4* rs   = (float4*)(smem + LDS_RS);

    // load frames s0-2 .. s0+63 (zero before sequence start)
    for (int i = tid; i < 66 * 75; i += 256) {
        int f = i / 75;
        int r = i - f * 75;
        int sg = s0 + f - 2;
        float v = 0.f;
        if (sg >= 0) v = poses[(size_t)(t0 + f - 2) * 75 + r];
        pbuf[i] = v;
    }
    __syncthreads();
    // per-frame root + 1/(max_dist+1e-8)
    if (tid < 66) {
        const float* P = pbuf + tid * 75;
        float r0 = P[0], r1 = P[1], r2 = P[2], m2 = 0.f;
        #pragma unroll
        for (int j = 0; j < 25; j++) {
            float x = P[j*3] - r0, y = P[j*3+1] - r1, z = P[j*3+2] - r2;
            m2 = fmaxf(m2, x*x + y*y + z*z);
        }
        float sc = 1.f / (sqrtf(m2) + 1e-8f);
        rs[tid] = make_float4(r0, r1, r2, sc);
    }
    __syncthreads();
    // in-place normalize
    for (int i = tid; i < 66 * 75; i += 256) {
        int f = i / 75;
        int r = i - f * 75;
        int c = r % 3;
        float4 q = rs[f];
        float rc = (c == 0) ? q.x : ((c == 1) ? q.y : q.z);
        pbuf[i] = (pbuf[i] - rc) * q.w;
    }
    __syncthreads();
    // 300 features per token -> bf16 feat tile
    unsigned short* feat = (unsigned short*)(smem + LDS_FEAT);
    for (int idx = tid; idx < MT_ * 300; idx += 256) {
        int tt = idx / 300;
        int k  = idx - tt * 300;
        int j  = k / 12;
        int c  = k - j * 12;
        int s  = s0 + tt;
        const float* Pc = pbuf + (tt + 2) * 75;   // p[s]; -75 = p[s-1]; -150 = p[s-2]
        float v = 0.f;
        if (c < 3) {
            v = Pc[j*3 + c];
        } else if (c < 6) {
            int cc = j*3 + c - 3;
            if (s >= 1) v = Pc[cc] - Pc[cc - 75];
        } else if (c < 9) {
            int cc = j*3 + c - 6;
            if (s >= 2)      v = Pc[cc] - 2.f * Pc[cc - 75] + Pc[cc - 150];
            else if (s == 1) v = Pc[cc] - Pc[cc - 75];      // acc[1] = vel[1]
        } else {
            int a = j*3 + c - 9;
            if (a < 39) {
                int e = a / 3, comp = a - e * 3;
                const float* A0 = Pc + d_c0[e] * 3;
                const float* A1 = Pc + d_c1[e] * 3;
                float x = A1[0]-A0[0], y = A1[1]-A0[1], z = A1[2]-A0[2];
                float n = fmaxf(sqrtf(x*x + y*y + z*z), 1e-12f);
                float tv = ((comp == 0) ? x : ((comp == 1) ? y : z)) / n;
                tv = fminf(fmaxf(tv, -1.f), 1.f);
                v = acosf(tv);
            }
        }
        v *= jw[j];
        feat[tt * 328 + k] = bf16_bits(v);
    }
    // zero K-pad columns 300..327
    for (int idx = tid; idx < MT_ * 28; idx += 256) {
        int tt = idx / 28;
        int k  = 300 + idx - tt * 28;
        feat[tt * 328 + k] = 0;
    }
    __syncthreads();

    // ---------------- phase 1: hidden = relu(feat @ W1' + b1') ----------------
    floatx4 acc[4][4];
    #pragma unroll
    for (int mi = 0; mi < 4; mi++)
        #pragma unroll
        for (int ni = 0; ni < 4; ni++) acc[mi][ni] = (floatx4){0.f, 0.f, 0.f, 0.f};

    // stage chunk 0 (16KB contiguous, lane-order == LDS order)
    #pragma unroll
    for (int i = 0; i < 4; i++) {
        int blk = i * 4 + wv;
        async16(smem + LDS_WB + blk * 1024 + lane * 16,
                (const char*)w1p + blk * 1024 + lane * 16);
    }
    __syncthreads();
    for (int kc = 0; kc < 10; kc++) {
        if (kc + 1 < 10) {                          // prefetch next chunk
            #pragma unroll
            for (int i = 0; i < 4; i++) {
                int blk = i * 4 + wv;
                async16(smem + LDS_WB + ((kc + 1) & 1) * 16384 + blk * 1024 + lane * 16,
                        (const char*)w1p + (kc + 1) * 16384 + blk * 1024 + lane * 16);
            }
        }
        short8 af[4], bf[4];
        const unsigned char* wb = smem + LDS_WB + (kc & 1) * 16384;
        #pragma unroll
        for (int mi = 0; mi < 4; mi++)   // A: 8 consecutive k at fixed m -> ds_read_b128
            af[mi] = *(const short8*)(smem + LDS_FEAT +
                     ((mi * 16 + (lane & 15)) * 328 + kc * 32 + (lane >> 4) * 8) * 2);
        #pragma unroll
        for (int ni = 0; ni < 4; ni++)   // B: pre-packed fragment order, conflict-free
            bf[ni] = *(const short8*)(wb + (wv * 4 + ni) * 1024 + lane * 16);
        #pragma unroll
        for (int mi = 0; mi < 4; mi++)
            #pragma unroll
            for (int ni = 0; ni < 4; ni++)
                acc[mi][ni] = __builtin_amdgcn_mfma_f32_16x16x32_bf16(
                    af[mi], bf[ni], acc[mi][ni], 0, 0, 0);
        __syncthreads();
    }

    // epilogue: +b1', relu, bf16, write hidden (A-layout row-major, 264 stride)
    unsigned short* hid = (unsigned short*)(smem + LDS_FEAT);
    float bv[4];
    #pragma unroll
    for (int ni = 0; ni < 4; ni++) bv[ni] = b1p[wv * 64 + ni * 16 + (lane & 15)];
    #pragma unroll
    for (int mi = 0; mi < 4; mi++)
        #pragma unroll
        for (int ni = 0; ni < 4; ni++)
            #pragma unroll
            for (int r = 0; r < 4; r++) {
                float v = fmaxf(acc[mi][ni][r] + bv[ni], 0.f);
                int m   = mi * 16 + (lane >> 4) * 4 + r;    // C/D: row=(l>>4)*4+r
                int col = wv * 64 + ni * 16 + (lane & 15);  //      col=l&15
                hid[m * 264 + col] = bf16_bits(v);
            }

    // ---------------- phase 2: out = hidden @ W2 + b2 ----------------
    #pragma unroll
    for (int i = 0; i < 2; i++) {                    // stage W2 chunk 0 (8KB)
        int blk = i * 4 + wv;
        async16(smem + LDS_WB + blk * 1024 + lane * 16,
                (const char*)w2p + blk * 1024 + lane * 16);
    }
    __syncthreads();                                 // hid writes + chunk0 visible

    floatx4 acc2[4][2];
    #pragma unroll
    for (int mi = 0; mi < 4; mi++)
        #pragma unroll
        for (int ni = 0; ni < 2; ni++) acc2[mi][ni] = (floatx4){0.f, 0.f, 0.f, 0.f};

    for (int kc = 0; kc < 8; kc++) {
        if (kc + 1 < 8) {
            #pragma unroll
            for (int i = 0; i < 2; i++) {
                int blk = i * 4 + wv;
                async16(smem + LDS_WB + ((kc + 1) & 1) * 16384 + blk * 1024 + lane * 16,
                        (const char*)w2p + (kc + 1) * 8192 + blk * 1024 + lane * 16);
            }
        }
        short8 af[4], bf2[2];
        const unsigned char* wb = smem + LDS_WB + (kc & 1) * 16384;
        #pragma unroll
        for (int mi = 0; mi < 4; mi++)
            af[mi] = *(const short8*)(smem + LDS_FEAT +
                     ((mi * 16 + (lane & 15)) * 264 + kc * 32 + (lane >> 4) * 8) * 2);
        #pragma unroll
        for (int ni = 0; ni < 2; ni++)
            bf2[ni] = *(const short8*)(wb + (wv * 2 + ni) * 1024 + lane * 16);
        #pragma unroll
        for (int mi = 0; mi < 4; mi++)
            #pragma unroll
            for (int ni = 0; ni < 2; ni++)
                acc2[mi][ni] = __builtin_amdgcn_mfma_f32_16x16x32_bf16(
                    af[mi], bf2[ni], acc2[mi][ni], 0, 0, 0);
        __syncthreads();
    }

    float c2[2];
    #pragma unroll
    for (int ni = 0; ni < 2; ni++) c2[ni] = b2[wv * 32 + ni * 16 + (lane & 15)];
    #pragma unroll
    for (int mi = 0; mi < 4; mi++)
        #pragma unroll
        for (int ni = 0; ni < 2; ni++)
            #pragma unroll
            for (int r = 0; r < 4; r++) {
                int m   = mi * 16 + (lane >> 4) * 4 + r;
                int col = wv * 32 + ni * 16 + (lane & 15);
                out[(size_t)(t0 + m) * 128 + col] = acc2[mi][ni][r] + c2[ni];
            }
}

// --------------------------- launch -----------------------------------------
extern "C" void kernel_launch(void* const* d_in, const int* in_sizes, int n_in,
                              void* d_out, int out_size, void* d_ws, size_t ws_size,
                              hipStream_t stream) {
    (void)in_sizes; (void)n_in; (void)out_size; (void)ws_size;
    const float* poses = (const float*)d_in[0];
    const float* W1    = (const float*)d_in[1];
    const float* b1    = (const float*)d_in[2];
    const float* gamma = (const float*)d_in[3];
    const float* beta  = (const float*)d_in[4];
    const float* rmean = (const float*)d_in[5];
    const float* rvar  = (const float*)d_in[6];
    const float* W2    = (const float*)d_in[7];
    const float* b2    = (const float*)d_in[8];
    const float* jw    = (const float*)d_in[9];

    unsigned short* w1p = (unsigned short*)d_ws;                 // 81920 bf16
    unsigned short* w2p = w1p + KPAD_ * HID_;                    // 32768 bf16
    float* b1p = (float*)((char*)d_ws + (KPAD_*HID_ + HID_*OUT_) * 2); // 256 fp32

    prep_kernel<<<450, 256, 0, stream>>>(W1, b1, gamma, beta, rmean, rvar, W2,
                                         w1p, w2p, b1p);
    pose_mlp<<<2048, 256, 0, stream>>>(poses, w1p, w2p, b1p, b2, jw, (float*)d_out);
}

// Round 2
// 159.727 us; speedup vs baseline: 2.2290x; 2.2290x over previous
//
#include <hip/hip_runtime.h>
#include <hip/hip_bf16.h>
#include <stdint.h>

// ---------------------------------------------------------------------------
// PoseFeatureExtractor fused kernel for MI355X (gfx950) — round 2
//   - no pose LDS staging: poses read from L1/L2, rs[] (root+scale) via atomicMax
//   - structured feature loops (per token-joint / token-edge), fast acos
//   - W1/W2 MFMA B-frags loaded global->registers (pre-packed): no W LDS,
//     no per-kc barriers (6 total vs 23)
//   - LDS 43.3KB -> 3 blocks/CU
// ---------------------------------------------------------------------------

#define S_    2048
#define MT_   64            // tokens per block (2048 % 64 == 0)
#define HID_  256
#define OUT_  128

typedef __attribute__((ext_vector_type(8))) short   short8;   // bf16x8 MFMA frag
typedef __attribute__((ext_vector_type(4))) float   floatx4;  // fp32x4 MFMA acc

__constant__ int d_c0[13] = {0,1,1,5,7,6,8,1,1,11,13,12,14};
__constant__ int d_c1[13] = {1,5,6,7,9,8,10,11,12,13,15,14,16};

__device__ __forceinline__ unsigned short bf16_bits(float v) {
    union { float f; unsigned u; } x; x.f = v;
    unsigned r = x.u + 0x7fffu + ((x.u >> 16) & 1u);   // RNE
    return (unsigned short)(r >> 16);
}

// |err| <= 6.7e-5 abs (A&S 4.4.45) — far below bf16 feature quantization
__device__ __forceinline__ float facos(float x) {
    float ax = fabsf(x);
    float p = fmaf(ax, -0.0187293f, 0.0742610f);
    p = fmaf(ax, p, -0.2121144f);
    p = fmaf(ax, p, 1.5707288f);
    float r = sqrtf(1.f - ax) * p;
    return x < 0.f ? 3.14159265358979f - r : r;
}

// --------------------------- prep kernel -----------------------------------
// Pack W1 (BN-folded, K padded 300->320) and W2 into bf16 MFMA-B-fragment
// order: frag block blk is contiguous 1KB; lane l holds B[k=(l>>4)*8+j][n=l&15]
// at bytes blk*1024 + l*16. One 16B coalesced store per thread; gather reads.
__global__ void prep_kernel(const float* __restrict__ W1, const float* __restrict__ b1,
                            const float* __restrict__ gamma, const float* __restrict__ beta,
                            const float* __restrict__ rmean, const float* __restrict__ rvar,
                            const float* __restrict__ W2,
                            unsigned short* __restrict__ w1p,
                            unsigned short* __restrict__ w2p,
                            float* __restrict__ b1p) {
    int idx = blockIdx.x * 256 + threadIdx.x;
    int lane = idx & 63;
    if (idx < 10240) {                       // W1: 160 frag-blocks (10 kc x 16 nt)
        int blk = idx >> 6;
        int kc = blk >> 4, nt = blk & 15;
        int n  = nt * 16 + (lane & 15);
        int k0 = kc * 32 + (lane >> 4) * 8;
        float a = gamma[n] * rsqrtf(rvar[n] + 1e-5f);
        short8 v;
        #pragma unroll
        for (int j = 0; j < 8; j++) {
            int k = k0 + j;
            float w = (k < 300) ? W1[k * HID_ + n] * a : 0.f;
            v[j] = (short)bf16_bits(w);
        }
        *(short8*)(w1p + blk * 512 + lane * 8) = v;
    } else if (idx < 14336) {                // W2: 64 frag-blocks (8 kc x 8 nt)
        int blk = (idx - 10240) >> 6;
        int kc = blk >> 3, nt = blk & 7;
        int n  = nt * 16 + (lane & 15);
        int k0 = kc * 32 + (lane >> 4) * 8;
        short8 v;
        #pragma unroll
        for (int j = 0; j < 8; j++)
            v[j] = (short)bf16_bits(W2[(k0 + j) * OUT_ + n]);
        *(short8*)(w2p + blk * 512 + lane * 8) = v;
    } else if (idx < 14592) {                // folded bias
        int n = idx - 14336;
        float a = gamma[n] * rsqrtf(rvar[n] + 1e-5f);
        b1p[n] = fmaf(a, b1[n] - rmean[n], beta[n]);
    }
}

// --------------------------- main fused kernel ------------------------------
// LDS: feat tile 64 x 328 ushort (stride 656B, bank-conflict-free for b128)
//      = 41984B; later reused as hidden 64 x 264 ushort. rs[66] float4 + rsm[66].
#define LDS_FEAT 0
#define LDS_RS   41984
#define LDS_RSM  (LDS_RS + 66 * 16)
#define LDS_TOT  (LDS_RSM + 66 * 4 + 8)   // 43312

__global__ __launch_bounds__(256, 3) void pose_mlp(
    const float* __restrict__ poses,
    const unsigned short* __restrict__ w1p,
    const unsigned short* __restrict__ w2p,
    const float* __restrict__ b1p,
    const float* __restrict__ b2,
    const float* __restrict__ jw,
    float* __restrict__ out)
{
    __shared__ __align__(16) unsigned char smem[LDS_TOT];
    const int tid  = threadIdx.x;
    const int lane = tid & 63;
    const int wv   = tid >> 6;
    const int t0   = blockIdx.x * MT_;
    const int s0   = t0 & (S_ - 1);

    // early-issue phase-1 kc=0 B-frags (deep in flight during phase 0)
    short8 bw[4];
    #pragma unroll
    for (int ni = 0; ni < 4; ni++)
        bw[ni] = *(const short8*)(w1p + (unsigned)(wv * 4 + ni) * 512 + lane * 8);

    unsigned short* feat = (unsigned short*)(smem + LDS_FEAT);
    float4*   rs  = (float4*)(smem + LDS_RS);
    unsigned* rsm = (unsigned*)(smem + LDS_RSM);

    // ---- phase 0a: per-frame root + 1/(max_dist+1e-8) via LDS atomicMax ----
    if (tid < 66) rsm[tid] = 0u;
    __syncthreads();
    for (int i = tid; i < 66 * 25; i += 256) {
        int f = i / 25, j = i - f * 25;
        int g = t0 - 2 + f; if (g < 0) g = 0;          // clamp; masked later
        const float* P = poses + (size_t)g * 75;
        float dx = P[j*3]   - P[0];
        float dy = P[j*3+1] - P[1];
        float dz = P[j*3+2] - P[2];
        float d2 = fmaf(dx, dx, fmaf(dy, dy, dz * dz));
        atomicMax(&rsm[f], __float_as_uint(d2));       // d2>=0: uint-order == float-order
    }
    __syncthreads();
    if (tid < 66) {
        int g = t0 - 2 + tid; if (g < 0) g = 0;
        const float* P = poses + (size_t)g * 75;
        float sc = 1.f / (sqrtf(__uint_as_float(rsm[tid])) + 1e-8f);
        rs[tid] = make_float4(P[0], P[1], P[2], sc);
    }
    __syncthreads();

    // ---- phase 0b: pos/vel/acc per (token, joint) — 1600 items ----
    for (int i = tid; i < MT_ * 25; i += 256) {
        int tt = i / 25, j = i - tt * 25;
        int s  = s0 + tt;
        int g  = t0 + tt;
        int g1 = g - 1 < 0 ? 0 : g - 1;
        int g2 = g - 2 < 0 ? 0 : g - 2;
        const float* Pc = poses + (size_t)g  * 75 + j * 3;
        const float* P1 = poses + (size_t)g1 * 75 + j * 3;
        const float* P2 = poses + (size_t)g2 * 75 + j * 3;
        float4 rc = rs[tt + 2], rm = rs[tt + 1], rp = rs[tt];
        float cx = (Pc[0] - rc.x) * rc.w, cy = (Pc[1] - rc.y) * rc.w, cz = (Pc[2] - rc.z) * rc.w;
        float mx = (P1[0] - rm.x) * rm.w, my = (P1[1] - rm.y) * rm.w, mz = (P1[2] - rm.z) * rm.w;
        float px = (P2[0] - rp.x) * rp.w, py = (P2[1] - rp.y) * rp.w, pz = (P2[2] - rp.z) * rp.w;
        bool h1 = (s >= 1), h2 = (s >= 2);
        float vx = h1 ? cx - mx : 0.f, vy = h1 ? cy - my : 0.f, vz = h1 ? cz - mz : 0.f;
        float ux = h2 ? mx - px : 0.f, uy = h2 ? my - py : 0.f, uz = h2 ? mz - pz : 0.f;
        float qx = vx - ux, qy = vy - uy, qz = vz - uz;   // acc (s==0 -> 0-0)
        float w = jw[j];
        unsigned short o0 = bf16_bits(cx * w), o1 = bf16_bits(cy * w), o2 = bf16_bits(cz * w);
        unsigned short o3 = bf16_bits(vx * w), o4 = bf16_bits(vy * w), o5 = bf16_bits(vz * w);
        unsigned short o6 = bf16_bits(qx * w), o7 = bf16_bits(qy * w), o8 = bf16_bits(qz * w);
        unsigned base = tt * 328 + j * 12;                 // even -> 4B-aligned pairs
        *(unsigned*)(feat + base)     = (unsigned)o0 | ((unsigned)o1 << 16);
        *(unsigned*)(feat + base + 2) = (unsigned)o2 | ((unsigned)o3 << 16);
        *(unsigned*)(feat + base + 4) = (unsigned)o4 | ((unsigned)o5 << 16);
        *(unsigned*)(feat + base + 6) = (unsigned)o6 | ((unsigned)o7 << 16);
        feat[base + 8] = o8;
    }

    // ---- phase 0c: angles per (token, edge) — 832 items ----
    // v/||v|| is invariant to root-centering + positive scaling -> raw coords
    for (int i = tid; i < MT_ * 13; i += 256) {
        int tt = i / 13, e = i - tt * 13;
        int g  = t0 + tt;
        const float* A = poses + (size_t)g * 75 + d_c1[e] * 3;
        const float* B = poses + (size_t)g * 75 + d_c0[e] * 3;
        float vx = A[0] - B[0], vy = A[1] - B[1], vz = A[2] - B[2];
        float n  = sqrtf(fmaf(vx, vx, fmaf(vy, vy, vz * vz)));
        float inv = 1.f / fmaxf(n, 1e-12f);
        float w = jw[e];
        float a0 = facos(fminf(fmaxf(vx * inv, -1.f), 1.f)) * w;
        float a1 = facos(fminf(fmaxf(vy * inv, -1.f), 1.f)) * w;
        float a2 = facos(fminf(fmaxf(vz * inv, -1.f), 1.f)) * w;
        unsigned base = tt * 328 + e * 12 + 9;             // odd
        feat[base] = bf16_bits(a0);
        *(unsigned*)(feat + base + 1) = (unsigned)bf16_bits(a1) | ((unsigned)bf16_bits(a2) << 16);
    }

    // ---- phase 0d: zero pad (angle slots j>=13 + K-pad 300..327) ----
    for (int i = tid; i < MT_ * 64; i += 256) {
        int tt = i >> 6, z = i & 63;
        int k;
        if (z < 36) { int jj = z / 3; k = (13 + jj) * 12 + 9 + (z - jj * 3); }
        else        { k = 300 + z - 36; }
        feat[tt * 328 + k] = 0;
    }
    __syncthreads();

    // ---- phase 1: hidden = relu(feat @ W1' + b1'), W-frags via registers ----
    floatx4 acc[4][4];
    #pragma unroll
    for (int mi = 0; mi < 4; mi++)
        #pragma unroll
        for (int ni = 0; ni < 4; ni++) acc[mi][ni] = (floatx4){0.f, 0.f, 0.f, 0.f};

    #pragma unroll 1
    for (int kc = 0; kc < 10; kc++) {
        short8 bn[4];
        if (kc < 9) {
            #pragma unroll
            for (int ni = 0; ni < 4; ni++)
                bn[ni] = *(const short8*)(w1p + (unsigned)((kc + 1) * 16 + wv * 4 + ni) * 512 + lane * 8);
        }
        short8 af[4];
        #pragma unroll
        for (int mi = 0; mi < 4; mi++)
            af[mi] = *(const short8*)(feat + (mi * 16 + (lane & 15)) * 328 + kc * 32 + (lane >> 4) * 8);
        #pragma unroll
        for (int mi = 0; mi < 4; mi++)
            #pragma unroll
            for (int ni = 0; ni < 4; ni++)
                acc[mi][ni] = __builtin_amdgcn_mfma_f32_16x16x32_bf16(
                    af[mi], bw[ni], acc[mi][ni], 0, 0, 0);
        if (kc < 9) {
            #pragma unroll
            for (int ni = 0; ni < 4; ni++) bw[ni] = bn[ni];
        }
    }

    // preload W2 kc=0 frags (independent of LDS), then barrier for hid overwrite
    short8 bw2[2];
    #pragma unroll
    for (int ni = 0; ni < 2; ni++)
        bw2[ni] = *(const short8*)(w2p + (unsigned)(wv * 2 + ni) * 512 + lane * 8);

    __syncthreads();   // all waves done reading feat

    unsigned short* hid = feat;                            // reuse, stride 264
    float bv[4];
    #pragma unroll
    for (int ni = 0; ni < 4; ni++) bv[ni] = b1p[wv * 64 + ni * 16 + (lane & 15)];
    #pragma unroll
    for (int mi = 0; mi < 4; mi++)
        #pragma unroll
        for (int ni = 0; ni < 4; ni++)
            #pragma unroll
            for (int r = 0; r < 4; r++) {
                float v = fmaxf(acc[mi][ni][r] + bv[ni], 0.f);
                int m   = mi * 16 + (lane >> 4) * 4 + r;   // C/D: row=(l>>4)*4+r
                int col = wv * 64 + ni * 16 + (lane & 15); //      col=l&15
                hid[m * 264 + col] = bf16_bits(v);
            }
    __syncthreads();   // hid visible

    // ---- phase 2: out = hidden @ W2 + b2 ----
    floatx4 acc2[4][2];
    #pragma unroll
    for (int mi = 0; mi < 4; mi++)
        #pragma unroll
        for (int ni = 0; ni < 2; ni++) acc2[mi][ni] = (floatx4){0.f, 0.f, 0.f, 0.f};

    #pragma unroll 1
    for (int kc = 0; kc < 8; kc++) {
        short8 bn2[2];
        if (kc < 7) {
            #pragma unroll
            for (int ni = 0; ni < 2; ni++)
                bn2[ni] = *(const short8*)(w2p + (unsigned)((kc + 1) * 8 + wv * 2 + ni) * 512 + lane * 8);
        }
        short8 af[4];
        #pragma unroll
        for (int mi = 0; mi < 4; mi++)
            af[mi] = *(const short8*)(hid + (mi * 16 + (lane & 15)) * 264 + kc * 32 + (lane >> 4) * 8);
        #pragma unroll
        for (int mi = 0; mi < 4; mi++)
            #pragma unroll
            for (int ni = 0; ni < 2; ni++)
                acc2[mi][ni] = __builtin_amdgcn_mfma_f32_16x16x32_bf16(
                    af[mi], bw2[ni], acc2[mi][ni], 0, 0, 0);
        if (kc < 7) {
            #pragma unroll
            for (int ni = 0; ni < 2; ni++) bw2[ni] = bn2[ni];
        }
    }

    float c2[2];
    #pragma unroll
    for (int ni = 0; ni < 2; ni++) c2[ni] = b2[wv * 32 + ni * 16 + (lane & 15)];
    #pragma unroll
    for (int mi = 0; mi < 4; mi++)
        #pragma unroll
        for (int ni = 0; ni < 2; ni++)
            #pragma unroll
            for (int r = 0; r < 4; r++) {
                int m   = mi * 16 + (lane >> 4) * 4 + r;
                int col = wv * 32 + ni * 16 + (lane & 15);
                out[(size_t)(t0 + m) * OUT_ + col] = acc2[mi][ni][r] + c2[ni];
            }
}

// --------------------------- launch -----------------------------------------
extern "C" void kernel_launch(void* const* d_in, const int* in_sizes, int n_in,
                              void* d_out, int out_size, void* d_ws, size_t ws_size,
                              hipStream_t stream) {
    (void)in_sizes; (void)n_in; (void)out_size; (void)ws_size;
    const float* poses = (const float*)d_in[0];
    const float* W1    = (const float*)d_in[1];
    const float* b1    = (const float*)d_in[2];
    const float* gamma = (const float*)d_in[3];
    const float* beta  = (const float*)d_in[4];
    const float* rmean = (const float*)d_in[5];
    const float* rvar  = (const float*)d_in[6];
    const float* W2    = (const float*)d_in[7];
    const float* b2    = (const float*)d_in[8];
    const float* jw    = (const float*)d_in[9];

    unsigned short* w1p = (unsigned short*)d_ws;                 // 320*256 bf16
    unsigned short* w2p = w1p + 320 * HID_;                      // 256*128 bf16
    float* b1p = (float*)((char*)d_ws + (320 * HID_ + HID_ * OUT_) * 2);

    prep_kernel<<<57, 256, 0, stream>>>(W1, b1, gamma, beta, rmean, rvar, W2,
                                        w1p, w2p, b1p);
    pose_mlp<<<2048, 256, 0, stream>>>(poses, w1p, w2p, b1p, b2, jw, (float*)d_out);
}